// Round 1
// baseline (175.888 us; speedup 1.0000x reference)
//
#include <hip/hip_runtime.h>
#include <hip/hip_bf16.h>
#include <stdint.h>

#define N_DIM 8192
#define D_DIM 512
#define BM 128
#define BN 128
#define BK 64

typedef __attribute__((ext_vector_type(8))) short bf16x8;
typedef __attribute__((ext_vector_type(4))) float f32x4;

__device__ __forceinline__ unsigned short f2bf(float f) {
    unsigned int x = __float_as_uint(f);
    x += 0x7fffu + ((x >> 16) & 1u);
    return (unsigned short)(x >> 16);
}

// ---------------- prep: f32 -> bf16, plus row squared norms ----------------
// grid: 2*N blocks (first N = U rows, next N = V rows), 256 threads, 2 elems/thread
__global__ void __launch_bounds__(256) prep_kernel(
    const float* __restrict__ U, const float* __restrict__ V,
    unsigned short* __restrict__ Ub, unsigned short* __restrict__ Vb,
    float* __restrict__ usq, float* __restrict__ vsq)
{
    int row = blockIdx.x;
    const float* src;
    unsigned short* dst;
    float* sq;
    if (row < N_DIM) {
        src = U + (size_t)row * D_DIM;
        dst = Ub + (size_t)row * D_DIM;
        sq  = usq + row;
    } else {
        int r = row - N_DIM;
        src = V + (size_t)r * D_DIM;
        dst = Vb + (size_t)r * D_DIM;
        sq  = vsq + r;
    }
    int t = threadIdx.x;
    float2 v = *reinterpret_cast<const float2*>(src + 2 * t);
    float s = v.x * v.x + v.y * v.y;
    ushort2 b;
    b.x = f2bf(v.x);
    b.y = f2bf(v.y);
    *reinterpret_cast<ushort2*>(dst + 2 * t) = b;

    #pragma unroll
    for (int o = 32; o > 0; o >>= 1) s += __shfl_down(s, o, 64);
    __shared__ float red[4];
    if ((t & 63) == 0) red[t >> 6] = s;
    __syncthreads();
    if (t == 0) *sq = red[0] + red[1] + red[2] + red[3];
}

// ---------------- fused GEMM + loss-reduction kernel ----------------
// 128x128 tile, 4 waves (2x2), each wave 64x64 via 4x4 x mfma 16x16x32 bf16.
// LDS layout per tile: [128 rows][64 k] bf16, 16B groups XOR-swizzled:
//   LDS(row, kg) holds global (row, kg ^ (row&7))   (kg = 16B group, 8 per row)
// Staged with global_load_lds (linear LDS dest, pre-swizzled global source).
__global__ void __launch_bounds__(256, 2) fused_kernel(
    const unsigned short* __restrict__ Ub, const unsigned short* __restrict__ Vb,
    const float* __restrict__ Mg, const float* __restrict__ Wg,
    const float* __restrict__ usq, const float* __restrict__ vsq,
    double* __restrict__ acc)
{
    __shared__ alignas(16) char As[BM * BK * 2];   // 16 KiB
    __shared__ alignas(16) char Bs[BN * BK * 2];   // 16 KiB
    __shared__ float red1[4], red2[4];

    const int t    = threadIdx.x;
    const int lane = t & 63;
    const int wave = t >> 6;
    const int wm   = wave >> 1;   // 0..1
    const int wn   = wave & 1;    // 0..1

    const int bid    = blockIdx.x;
    const int tile_m = bid >> 6;
    const int tile_n = bid & 63;
    const int row0   = tile_m * BM;
    const int col0   = tile_n * BN;

    const f32x4 zero = {0.f, 0.f, 0.f, 0.f};
    f32x4 acc_r[4][4];
    #pragma unroll
    for (int i = 0; i < 4; ++i)
        #pragma unroll
        for (int j = 0; j < 4; ++j)
            acc_r[i][j] = zero;

    auto As3 = (__attribute__((address_space(3))) char*)As;
    auto Bs3 = (__attribute__((address_space(3))) char*)Bs;

    for (int kt = 0; kt < D_DIM / BK; ++kt) {
        const int k0 = kt * BK;
        // stage A and B tiles: 1024 16B slots each, 4 per thread
        #pragma unroll
        for (int c = 0; c < 4; ++c) {
            int s   = c * 256 + t;
            int row = s >> 3;
            int kg  = s & 7;
            int kgs = kg ^ (row & 7);    // inverse-swizzled global source
            const unsigned short* ga = Ub + (size_t)(row0 + row) * D_DIM + k0 + kgs * 8;
            __builtin_amdgcn_global_load_lds(
                (const __attribute__((address_space(1))) void*)ga,
                (__attribute__((address_space(3))) void*)(As3 + s * 16), 16, 0, 0);
            const unsigned short* gb = Vb + (size_t)(col0 + row) * D_DIM + k0 + kgs * 8;
            __builtin_amdgcn_global_load_lds(
                (const __attribute__((address_space(1))) void*)gb,
                (__attribute__((address_space(3))) void*)(Bs3 + s * 16), 16, 0, 0);
        }
        __syncthreads();

        #pragma unroll
        for (int kc = 0; kc < 2; ++kc) {
            bf16x8 af[4], bfr[4];
            const int kgw = kc * 4 + (lane >> 4);
            #pragma unroll
            for (int i = 0; i < 4; ++i) {
                int ra   = wm * 64 + i * 16 + (lane & 15);
                int offa = ra * (BK * 2) + ((kgw ^ (ra & 7)) * 16);
                af[i] = *reinterpret_cast<const bf16x8*>(As + offa);
                int rb   = wn * 64 + i * 16 + (lane & 15);
                int offb = rb * (BK * 2) + ((kgw ^ (rb & 7)) * 16);
                bfr[i] = *reinterpret_cast<const bf16x8*>(Bs + offb);
            }
            #pragma unroll
            for (int i = 0; i < 4; ++i)
                #pragma unroll
                for (int j = 0; j < 4; ++j)
                    acc_r[i][j] = __builtin_amdgcn_mfma_f32_16x16x32_bf16(
                        af[i], bfr[j], acc_r[i][j], 0, 0, 0);
        }
        __syncthreads();
    }

    // ---- fused epilogue: read M/W once, reduce both loss terms ----
    // C/D layout (16x16x32): col = lane&15, row = (lane>>4)*4 + reg
    float us[4][4];
    #pragma unroll
    for (int i = 0; i < 4; ++i) {
        int r0 = row0 + wm * 64 + i * 16 + (lane >> 4) * 4;
        #pragma unroll
        for (int q = 0; q < 4; ++q) us[i][q] = usq[r0 + q];
    }
    float vsn[4];
    #pragma unroll
    for (int j = 0; j < 4; ++j)
        vsn[j] = vsq[col0 + wn * 64 + j * 16 + (lane & 15)];

    float s1 = 0.f, s2 = 0.f;
    #pragma unroll
    for (int i = 0; i < 4; ++i) {
        int rbase = row0 + wm * 64 + i * 16 + (lane >> 4) * 4;
        #pragma unroll
        for (int j = 0; j < 4; ++j) {
            int cidx = col0 + wn * 64 + j * 16 + (lane & 15);
            #pragma unroll
            for (int q = 0; q < 4; ++q) {
                size_t idx = (size_t)(rbase + q) * N_DIM + cidx;
                float rec = acc_r[i][j][q];
                float m   = Mg[idx];
                float w   = Wg[idx];
                float d   = rec - m;
                s1 = fmaf(d, d, s1);
                s2 = fmaf(w, us[i][q] + vsn[j] - 2.f * rec, s2);
            }
        }
    }

    #pragma unroll
    for (int o = 32; o > 0; o >>= 1) {
        s1 += __shfl_down(s1, o, 64);
        s2 += __shfl_down(s2, o, 64);
    }
    if (lane == 0) { red1[wave] = s1; red2[wave] = s2; }
    __syncthreads();
    if (t == 0) {
        double a1 = (double)red1[0] + red1[1] + red1[2] + red1[3];
        double a2 = (double)red2[0] + red2[1] + red2[2] + red2[3];
        atomicAdd(acc, a1);
        atomicAdd(acc + 1, a2);
    }
}

// ---------------- finalize ----------------
__global__ void finalize_kernel(const double* __restrict__ acc,
                                const float* __restrict__ alpha,
                                float* __restrict__ out)
{
    double tot = acc[0] + (double)alpha[0] * acc[1];
    out[0] = (float)(tot / ((double)N_DIM * (double)N_DIM));
}

extern "C" void kernel_launch(void* const* d_in, const int* in_sizes, int n_in,
                              void* d_out, int out_size, void* d_ws, size_t ws_size,
                              hipStream_t stream) {
    const float* U     = (const float*)d_in[0];
    const float* V     = (const float*)d_in[1];
    const float* Mg    = (const float*)d_in[2];
    const float* Wg    = (const float*)d_in[3];
    const float* alpha = (const float*)d_in[4];

    char* ws = (char*)d_ws;
    unsigned short* Ub = (unsigned short*)ws;                          // 8 MiB
    unsigned short* Vb = (unsigned short*)(ws + 8u * 1024 * 1024);     // 8 MiB
    float* usq = (float*)(ws + 16u * 1024 * 1024);                     // 32 KiB
    float* vsq = (float*)(ws + 16u * 1024 * 1024 + 32u * 1024);       // 32 KiB
    double* acc = (double*)(ws + 16u * 1024 * 1024 + 64u * 1024);     // 16 B

    hipMemsetAsync(acc, 0, 2 * sizeof(double), stream);
    prep_kernel<<<2 * N_DIM, 256, 0, stream>>>(U, V, Ub, Vb, usq, vsq);
    fused_kernel<<<(N_DIM / BM) * (N_DIM / BN), 256, 0, stream>>>(
        Ub, Vb, Mg, Wg, usq, vsq, acc);
    finalize_kernel<<<1, 1, 0, stream>>>(acc, alpha, (float*)d_out);
}